// Round 13
// baseline (337.509 us; speedup 1.0000x reference)
//
#include <hip/hip_runtime.h>

typedef float v2f __attribute__((ext_vector_type(2)));
typedef float v4f __attribute__((ext_vector_type(4)));

#define RAD 3
#define TW  256              // tile width  (64 lanes x 4 cols)
#define TH  16               // tile height (4 waves x 4 rows, 2 steps of row-pair)
#define LROWS (TH + 2*RAD)   // 22
#define PITCH 264            // LDS row pitch (floats); 1056 B, b128-aligned

#define LOG2E 1.4426950408889634f
// color coefficient pre-scaled into fast-exp integer domain: -50*log2(e)*2^23
#define KC2_23 (-50.0f * LOG2E * 8388608.0f)

// Fast-exp2 magic per tap position: exponent bias + balanced pw-linear offset
// + spatial weight, all folded (proven absmax-neutral in R9/R12).
// Out-of-range dy -> DEAD: y stays in [5e6, 6.1e8] -> w is denormal (~0).
__device__ __forceinline__ constexpr float MAGICV(int dy, int dx) {
    if (dy < 0 || dy > 6) return 6.1e8f;   // dead slot: w ~ 2^-55 ~ 0
    const int k = (dy - 3) * (dy - 3) + (dx - 3) * (dx - 3);
    return (127.0f - 0.0425f - (float)k * 0.08014973f) * 8388608.0f;
}

__global__ __launch_bounds__(256) void bilateral_kernel(
    const float* __restrict__ in, float* __restrict__ out, int H, int W)
{
    __shared__ float tile[LROWS * PITCH];

    const int tx = threadIdx.x;              // 0..63
    const int ty = threadIdx.y;              // 0..3 (wave id)
    const int gx0 = blockIdx.x * TW;
    const int gy0 = blockIdx.y * TH;
    const size_t plane = (size_t)blockIdx.z * H * W;
    const float* __restrict__ p = in + plane;
    float* __restrict__ q = out + plane;

    // ---- Stage 22 x 264 tile (tile col c <-> global col gx0 + c - 4) ----
    const bool xedge = (blockIdx.x == 0) || (blockIdx.x == gridDim.x - 1);
    for (int r = ty; r < LROWS; r += 4) {
        const int gy = min(max(gy0 + r - RAD, 0), H - 1);
        const float* rp = p + (size_t)gy * W;
        for (int qd = tx; qd < PITCH / 4; qd += 64) {
            const int gc = gx0 - 4 + 4 * qd;
            v4f val;
            if (!xedge || (gc >= 0 && gc + 3 < W)) {
                val = *reinterpret_cast<const v4f*>(rp + gc);
            } else {
                #pragma unroll
                for (int e = 0; e < 4; ++e) {
                    const int c = min(max(gc + e, 0), W - 1);
                    val[e] = rp[c];
                }
            }
            *reinterpret_cast<v4f*>(&tile[r * PITCH + 4 * qd]) = val;
        }
    }
    __syncthreads();

    const v2f K2v = {KC2_23, KC2_23};

    // Each wave owns rows [4*ty, 4*ty+4); 2 steps of a vertical pixel pair.
    // The two centers of the pair are PACKED into one v2f -> v_pk_*_f32 math.
    #pragma unroll 1
    for (int step = 0; step < 2; ++step) {
        const int ory = ty * 4 + step * 2;   // output rows ory, ory+1 (tile-relative)

        const v4f xc0 = *reinterpret_cast<const v4f*>(&tile[(ory + 3) * PITCH + 4 * tx + 4]);
        const v4f xc1 = *reinterpret_cast<const v4f*>(&tile[(ory + 4) * PITCH + 4 * tx + 4]);

        v2f x2[4], num2[4], den2[4];
        #pragma unroll
        for (int pp = 0; pp < 4; ++pp) {
            x2[pp]   = (v2f){xc0[pp], xc1[pp]};
            num2[pp] = (v2f){0.f, 0.f};
            den2[pp] = (v2f){0.f, 0.f};
        }

        // Sample row ory+rr: lo half = center0 tap (dy=rr), hi half = center1 (dy=rr-1).
        #pragma unroll
        for (int rr = 0; rr < 8; ++rr) {
            const float* rowp = &tile[(ory + rr) * PITCH + 4 * tx];
            const v4f ra = *reinterpret_cast<const v4f*>(rowp);
            const v4f rb = *reinterpret_cast<const v4f*>(rowp + 4);
            const v4f rc = *reinterpret_cast<const v4f*>(rowp + 8);
            const float v[12] = {ra.x, ra.y, ra.z, ra.w,
                                 rb.x, rb.y, rb.z, rb.w,
                                 rc.x, rc.y, rc.z, rc.w};

            #pragma unroll
            for (int dx = 0; dx < 7; ++dx) {
                #pragma unroll
                for (int pp = 0; pp < 4; ++pp) {
                    const float s = v[1 + pp + dx];
                    const v2f s2 = {s, s};
                    const v2f m2 = {MAGICV(rr, dx), MAGICV(rr - 1, dx)};
                    const v2f d2 = s2 - x2[pp];
                    const v2f t2 = d2 * K2v;
                    const v2f y2 = __builtin_elementwise_fma(t2, d2, m2);
                    const v2f w2 = {__int_as_float((int)y2.x),
                                    __int_as_float((int)y2.y)};
                    num2[pp] = __builtin_elementwise_fma(w2, s2, num2[pp]);
                    den2[pp] = den2[pp] + w2;
                }
            }
        }

        v4f o0, o1;
        #pragma unroll
        for (int pp = 0; pp < 4; ++pp) {
            o0[pp] = num2[pp].x * __builtin_amdgcn_rcpf(den2[pp].x);
            o1[pp] = num2[pp].y * __builtin_amdgcn_rcpf(den2[pp].y);
        }
        float* q0 = q + (size_t)(gy0 + ory) * W + gx0 + 4 * tx;
        *reinterpret_cast<v4f*>(q0)     = o0;
        *reinterpret_cast<v4f*>(q0 + W) = o1;
    }
}

extern "C" void kernel_launch(void* const* d_in, const int* in_sizes, int n_in,
                              void* d_out, int out_size, void* d_ws, size_t ws_size,
                              hipStream_t stream)
{
    const float* in = (const float*)d_in[0];
    float* out = (float*)d_out;

    const int H = 1024, W = 1024;
    const int planes = in_sizes[0] / (H * W);       // 48

    dim3 grid(W / TW, H / TH, planes);              // 4 x 64 x 48
    dim3 block(64, 4, 1);
    bilateral_kernel<<<grid, block, 0, stream>>>(in, out, H, W);
}

// Round 14
// 284.134 us; speedup vs baseline: 1.1879x; 1.1879x over previous
//
#include <hip/hip_runtime.h>

typedef float v4f __attribute__((ext_vector_type(4)));

#define RAD 3
#define TW  256              // tile width  (64 lanes x 4 cols)
#define TH  8                // tile height (4 waves x 2 rows)
#define LROWS (TH + 2*RAD)   // 14
#define PITCH 264            // LDS row pitch (floats); 1056 B, b128-aligned
                             // LDS = 14*264*4 = 14784 B -> thread-limited 8 blocks/CU

#define LOG2E 1.4426950408889634f
// Tile is stored PRE-SCALED by SC = sqrt(50*log2e*2^23); then
// (SC*s - SC*x)^2 = 50*log2e*2^23 * d^2  -- the tap's mul disappears.
#define SC      24598.987f
#define INV_SC  (1.0f / 24598.987f)

// Fast-exp2 magic per tap position, folding: exponent bias (127), balanced
// piecewise-linear error offset (-0.0425 in log2), and the spatial weight
// log2(ws) = -k/(18*ln2), k = (dy-3)^2+(dx-3)^2.   All compile-time.
// y = M - u^2 in [4.5e8, 1.07e9]: positive, < 2^31, bits are a normal f32.
__device__ __forceinline__ constexpr float MAGIC(int dy, int dx) {
    const int k = (dy - 3) * (dy - 3) + (dx - 3) * (dx - 3);
    return (127.0f - 0.0425f - (float)k * 0.08014973f) * 8388608.0f;
}

// w = ws * 2^(-50*log2e*d^2):  y = fma(u, -u, M);  w = bits(int(y)).
__device__ __forceinline__ float fastw(float u, float M) {
    const float y = fmaf(u, -u, M);
    return __int_as_float((int)y);
}

__global__ __launch_bounds__(256) void bilateral_kernel(
    const float* __restrict__ in, float* __restrict__ out, int H, int W)
{
    __shared__ float tile[LROWS * PITCH];

    const int tx = threadIdx.x;              // 0..63
    const int ty = threadIdx.y;              // 0..3 (wave id)
    const int gx0 = blockIdx.x * TW;
    const int gy0 = blockIdx.y * TH;
    const size_t plane = (size_t)blockIdx.z * H * W;
    const float* __restrict__ p = in + plane;
    float* __restrict__ q = out + plane;

    // ---- Stage 14 x 264 tile, PRE-SCALED by SC (col c <-> global gx0+c-4) ----
    const bool xedge = (blockIdx.x == 0) || (blockIdx.x == gridDim.x - 1);
    for (int r = ty; r < LROWS; r += 4) {
        const int gy = min(max(gy0 + r - RAD, 0), H - 1);
        const float* rp = p + (size_t)gy * W;
        for (int qd = tx; qd < PITCH / 4; qd += 64) {
            const int gc = gx0 - 4 + 4 * qd;
            v4f val;
            if (!xedge || (gc >= 0 && gc + 3 < W)) {
                val = *reinterpret_cast<const v4f*>(rp + gc);
            } else {
                #pragma unroll
                for (int e = 0; e < 4; ++e) {
                    const int c = min(max(gc + e, 0), W - 1);
                    val[e] = rp[c];
                }
            }
            val *= SC;
            *reinterpret_cast<v4f*>(&tile[r * PITCH + 4 * qd]) = val;
        }
    }
    __syncthreads();

    // Each wave owns 2 output rows, processed one at a time (minimal live state).
    #pragma unroll 1
    for (int j = 0; j < 2; ++j) {
        const int ory = ty * 2 + j;          // tile-relative output row 0..7

        // Centers (pre-scaled): tile row ory+3, tile cols 4tx+4 .. 4tx+7
        const v4f cx = *reinterpret_cast<const v4f*>(&tile[(ory + 3) * PITCH + 4 * tx + 4]);

        float num[4] = {0.f, 0.f, 0.f, 0.f};
        float den[4] = {0.f, 0.f, 0.f, 0.f};

        #pragma unroll
        for (int rr = 0; rr < 7; ++rr) {     // window rows, dy = rr
            const float* rowp = &tile[(ory + rr) * PITCH + 4 * tx];
            const v4f ra = *reinterpret_cast<const v4f*>(rowp);
            const v4f rb = *reinterpret_cast<const v4f*>(rowp + 4);
            const v4f rc = *reinterpret_cast<const v4f*>(rowp + 8);
            const float v[12] = {ra.x, ra.y, ra.z, ra.w,
                                 rb.x, rb.y, rb.z, rb.w,
                                 rc.x, rc.y, rc.z, rc.w};

            #pragma unroll
            for (int dx = 0; dx < 7; ++dx) {
                #pragma unroll
                for (int pp = 0; pp < 4; ++pp) {
                    const float cs = v[1 + pp + dx];      // pre-scaled sample
                    const float w = fastw(cs - cx[pp], MAGIC(rr, dx));
                    num[pp] = fmaf(w, cs, num[pp]);       // num' = SC * true num
                    den[pp] += w;
                }
            }
        }

        v4f o;
        #pragma unroll
        for (int pp = 0; pp < 4; ++pp)
            o[pp] = num[pp] * __builtin_amdgcn_rcpf(den[pp]) * INV_SC;
        *reinterpret_cast<v4f*>(q + (size_t)(gy0 + ory) * W + gx0 + 4 * tx) = o;
    }
}

extern "C" void kernel_launch(void* const* d_in, const int* in_sizes, int n_in,
                              void* d_out, int out_size, void* d_ws, size_t ws_size,
                              hipStream_t stream)
{
    const float* in = (const float*)d_in[0];
    float* out = (float*)d_out;

    const int H = 1024, W = 1024;
    const int planes = in_sizes[0] / (H * W);       // 48

    dim3 grid(W / TW, H / TH, planes);              // 4 x 128 x 48
    dim3 block(64, 4, 1);
    bilateral_kernel<<<grid, block, 0, stream>>>(in, out, H, W);
}